// Round 1
// baseline (183.787 us; speedup 1.0000x reference)
//
#include <hip/hip_runtime.h>

// Spatial transformer: trilinear warp of src by flow, border padding.
// D=160, H=192, W=160.  u = (idx + flow) * S/(S-1) - 0.5, clamp, trilinear.
//
// Lineage: R6 (4-parity table, 1x16B gather/voxel, warp=50us) showed req-count
// 2->1 is free => limiter is DISTINCT LINES serviced from L3 (39MB table,
// 6.4MB/XCD window > 4MB L2). R7: z-parity-only table (19.7MB), 2x dwordx2
// gathers/voxel, (d-slab x h-half) block ordering => ~2.6MB/XCD active window
// fits L2; pack swizzled so each XCD builds its own slab.

#define DD 160
#define HH 192
#define WW 160
#define DHW (DD * HH * WW)
#define ZP (DD / 2)   /* 80 */
#define TAB_ENTRIES (2 * ZP * HH * WW)        /* 4,915,200 u32 = 19,660,800 B */
#define WS_NEEDED (4ULL * TAB_ENTRIES)

typedef unsigned int u32x2 __attribute__((ext_vector_type(2)));

__device__ __forceinline__ unsigned short bf16_rn(float f) {
    unsigned int u = __float_as_uint(f);
    return (unsigned short)((u + 0x7FFFu + ((u >> 16) & 1u)) >> 16);
}

// ---------------- prepass: z-parity-packed bf16 table ----------------
// tab[cz][zp][y][x] (u32) = bf16(src[2zp+cz, y, x]) | bf16(src[min(2zp+cz+1,DD-1), y, x]) << 16
// XCD swizzle matches warp2: XCD k builds zp in [10k, 10k+10) -> slab lands in
// (or at least streams through) the L2 that will gather from it.
__global__ __launch_bounds__(256) void pack2_kernel(
    const float* __restrict__ src, unsigned int* __restrict__ tab)
{
    int b = blockIdx.x;
    int nb = (b & 7) * 300 + (b >> 3);              // grid 2400 = 8 * 300
    int t = nb * 256 + (int)threadIdx.x;            // 614,400 threads
    int xq  = t % (WW / 4);
    int rem = t / (WW / 4);
    int y   = rem % HH;
    int zp  = rem / HH;                             // [0,80)
    int x = xq * 4;

    int za = 2 * zp;
    int zb = 2 * zp + 1;
    int zc = min(2 * zp + 2, DD - 1);

    const float4 ra = *(const float4*)(src + ((size_t)za * HH + y) * WW + x);
    const float4 rb = *(const float4*)(src + ((size_t)zb * HH + y) * WW + x);
    const float4 rc = *(const float4*)(src + ((size_t)zc * HH + y) * WW + x);

    unsigned int e0[4], e1[4];
    #pragma unroll
    for (int k = 0; k < 4; ++k) {
        float a = ((const float*)&ra)[k];
        float m = ((const float*)&rb)[k];
        float c = ((const float*)&rc)[k];
        unsigned int bm = (unsigned int)bf16_rn(m);
        e0[k] = (unsigned int)bf16_rn(a) | (bm << 16);            // cz=0: (2zp, 2zp+1)
        e1[k] = bm | ((unsigned int)bf16_rn(c) << 16);            // cz=1: (2zp+1, 2zp+2 clamped)
    }
    size_t o0 = ((size_t)(0 * ZP + zp) * HH + y) * WW + x;
    size_t o1 = ((size_t)(1 * ZP + zp) * HH + y) * WW + x;
    *(uint4*)(tab + o0) = make_uint4(e0[0], e0[1], e0[2], e0[3]);
    *(uint4*)(tab + o1) = make_uint4(e1[0], e1[1], e1[2], e1[3]);
}

// ---------------- main: 2x 8B gathers per voxel, L2-resident slab ----------------
__device__ __forceinline__ float lerp8(u32x2 A, u32x2 B, bool xe,
                                       float fx, float fy, float fz)
{
    unsigned int ta0 = A.x, ta1 = A.y;   // row y0: entries x0, x1 (each = z0|z1<<16)
    unsigned int tb0 = B.x, tb1 = B.y;   // row y1
    unsigned int a0 = xe ? ta1 : ta0;    // x0==WW-1: both x taps = entry x1
    unsigned int b0 = xe ? tb1 : tb0;

    float c000 = __uint_as_float(a0 << 16);
    float c100 = __uint_as_float(a0 & 0xFFFF0000u);
    float c001 = __uint_as_float(ta1 << 16);
    float c101 = __uint_as_float(ta1 & 0xFFFF0000u);
    float c010 = __uint_as_float(b0 << 16);
    float c110 = __uint_as_float(b0 & 0xFFFF0000u);
    float c011 = __uint_as_float(tb1 << 16);
    float c111 = __uint_as_float(tb1 & 0xFFFF0000u);

    float r00 = fmaf(fx, c001 - c000, c000);
    float r01 = fmaf(fx, c011 - c010, c010);
    float r10 = fmaf(fx, c101 - c100, c100);
    float r11 = fmaf(fx, c111 - c110, c110);
    float r0  = fmaf(fy, r01 - r00, r00);
    float r1  = fmaf(fy, r11 - r10, r10);
    return fmaf(fz, r1 - r0, r0);
}

__global__ __launch_bounds__(256) void warp2_kernel(
    const unsigned int* __restrict__ tab,
    const float* __restrict__ flow,
    float* __restrict__ out)
{
    // Block -> voxel mapping: XCD k owns d in [20k, 20k+20); within the slab,
    // iterate h-half 0 fully, then h-half 1. Active window per XCD (~256
    // resident blocks) => ~17 d-planes x half-y => ~2.6 MB of table: L2-fits.
    int b  = blockIdx.x;                 // grid 4800 = 8 * 2 * 20 * 15
    int k  = b & 7;                      // XCD
    int j  = b >> 3;                     // [0,600)
    int hh = j / 300;                    // h half: 0 or 1
    int jj = j - hh * 300;               // [0,300)
    int dq = jj / 15;                    // [0,20)
    int r  = jj - dq * 15;               // [0,15): 15 blocks cover one half-plane

    int base = (k * 20 + dq) * (HH * WW) + hh * ((HH / 2) * WW)
             + r * 1024 + (int)threadIdx.x * 4;

    int w = base % WW;
    int tmp = base / WW;
    int h = tmp % HH;
    int d = tmp / HH;

    const float4 f0  = *(const float4*)(flow + base);           // -> D/z
    const float4 f1  = *(const float4*)(flow + DHW + base);     // -> H/y
    const float4 f2v = *(const float4*)(flow + 2 * DHW + base); // -> W/x
    const float* fl0 = (const float*)&f0;
    const float* fl1 = (const float*)&f1;
    const float* fl2 = (const float*)&f2v;

    const float SX = (float)WW / (float)(WW - 1);
    const float SY = (float)HH / (float)(HH - 1);
    const float SZ = (float)DD / (float)(DD - 1);

    float fx[4], fy[4], fz[4];
    bool  xe[4];
    const unsigned int* pa[4];
    const unsigned int* pb[4];

    // ---- phase 1: addresses & weights (consumes flow) ----
    #pragma unroll
    for (int v = 0; v < 4; ++v) {
        float ux = fmaf((float)(w + v) + fl2[v], SX, -0.5f);
        float uy = fmaf((float)h + fl1[v],       SY, -0.5f);
        float uz = fmaf((float)d + fl0[v],       SZ, -0.5f);
        ux = fminf(fmaxf(ux, 0.0f), (float)(WW - 1));
        uy = fminf(fmaxf(uy, 0.0f), (float)(HH - 1));
        uz = fminf(fmaxf(uz, 0.0f), (float)(DD - 1));
        float x0f = floorf(ux), y0f = floorf(uy), z0f = floorf(uz);
        fx[v] = ux - x0f; fy[v] = uy - y0f; fz[v] = uz - z0f;
        int x0 = (int)x0f, y0 = (int)y0f, z0 = (int)z0f;
        int cz = z0 & 1, zp = z0 >> 1;
        int y1 = min(y0 + 1, HH - 1);
        int xb = min(x0, WW - 2);
        xe[v] = (x0 == WW - 1);
        const unsigned int* rowz = tab + (size_t)(cz * ZP + zp) * (HH * WW);
        pa[v] = rowz + (size_t)y0 * WW + xb;
        pb[v] = rowz + (size_t)y1 * WW + xb;
    }

    // ---- phase 2: issue all 8 gathers (addr is 4B-aligned; dwordx2 needs dword align) ----
    u32x2 qa[4], qb[4];
    #pragma unroll
    for (int v = 0; v < 4; ++v) {
        asm volatile("global_load_dwordx2 %0, %1, off" : "=v"(qa[v]) : "v"(pa[v]));
        asm volatile("global_load_dwordx2 %0, %1, off" : "=v"(qb[v]) : "v"(pb[v]));
    }

    // ---- phase 3: progressive waits (vmcnt retires in issue order) + interp ----
    float res[4];
    asm volatile("s_waitcnt vmcnt(6)" : "+v"(qa[0]), "+v"(qb[0]) :: "memory");
    res[0] = lerp8(qa[0], qb[0], xe[0], fx[0], fy[0], fz[0]);
    asm volatile("s_waitcnt vmcnt(4)" : "+v"(qa[1]), "+v"(qb[1]) :: "memory");
    res[1] = lerp8(qa[1], qb[1], xe[1], fx[1], fy[1], fz[1]);
    asm volatile("s_waitcnt vmcnt(2)" : "+v"(qa[2]), "+v"(qb[2]) :: "memory");
    res[2] = lerp8(qa[2], qb[2], xe[2], fx[2], fy[2], fz[2]);
    asm volatile("s_waitcnt vmcnt(0)" : "+v"(qa[3]), "+v"(qb[3]) :: "memory");
    res[3] = lerp8(qa[3], qb[3], xe[3], fx[3], fy[3], fz[3]);

    *(float4*)(out + base) = make_float4(res[0], res[1], res[2], res[3]);
}

// ---------------- fallback (proven R2 kernel) if ws too small ----------------
struct __align__(4) F2 { float a, b; };

__global__ __launch_bounds__(256) void warp_direct_kernel(
    const float* __restrict__ src,
    const float* __restrict__ flow,
    float* __restrict__ out)
{
    int b = blockIdx.x;
    int nb = (b & 7) * 600 + (b >> 3);
    int base = (nb * 256 + (int)threadIdx.x) * 4;

    int w = base % WW;
    int tmp = base / WW;
    int h = tmp % HH;
    int d = tmp / HH;

    const float4 f0  = *(const float4*)(flow + base);
    const float4 f1  = *(const float4*)(flow + DHW + base);
    const float4 f2v = *(const float4*)(flow + 2 * DHW + base);
    const float* f0p = (const float*)&f0;
    const float* f1p = (const float*)&f1;
    const float* f2p = (const float*)&f2v;

    const float SX = (float)WW / (float)(WW - 1);
    const float SY = (float)HH / (float)(HH - 1);
    const float SZ = (float)DD / (float)(DD - 1);

    float res[4];
    #pragma unroll
    for (int v = 0; v < 4; ++v) {
        float ux = fmaf((float)(w + v) + f2p[v], SX, -0.5f);
        float uy = fmaf((float)h + f1p[v],       SY, -0.5f);
        float uz = fmaf((float)d + f0p[v],       SZ, -0.5f);
        ux = fminf(fmaxf(ux, 0.0f), (float)(WW - 1));
        uy = fminf(fmaxf(uy, 0.0f), (float)(HH - 1));
        uz = fminf(fmaxf(uz, 0.0f), (float)(DD - 1));
        float x0f = floorf(ux), y0f = floorf(uy), z0f = floorf(uz);
        float fx = ux - x0f, fy = uy - y0f, fz = uz - z0f;
        int x0 = (int)x0f, y0 = (int)y0f, z0 = (int)z0f;
        int y1 = min(y0 + 1, HH - 1);
        int z1 = min(z0 + 1, DD - 1);
        int xb = min(x0, WW - 2);
        bool xe = (x0 == WW - 1);
        F2 q00 = *(const F2*)(src + ((size_t)z0 * HH + y0) * WW + xb);
        F2 q01 = *(const F2*)(src + ((size_t)z0 * HH + y1) * WW + xb);
        F2 q10 = *(const F2*)(src + ((size_t)z1 * HH + y0) * WW + xb);
        F2 q11 = *(const F2*)(src + ((size_t)z1 * HH + y1) * WW + xb);
        float c000 = xe ? q00.b : q00.a, c001 = q00.b;
        float c010 = xe ? q01.b : q01.a, c011 = q01.b;
        float c100 = xe ? q10.b : q10.a, c101 = q10.b;
        float c110 = xe ? q11.b : q11.a, c111 = q11.b;
        float r00 = fmaf(fx, c001 - c000, c000);
        float r01 = fmaf(fx, c011 - c010, c010);
        float r10 = fmaf(fx, c101 - c100, c100);
        float r11 = fmaf(fx, c111 - c110, c110);
        float r0  = fmaf(fy, r01 - r00, r00);
        float r1  = fmaf(fy, r11 - r10, r10);
        res[v]    = fmaf(fz, r1 - r0, r0);
    }
    *(float4*)(out + base) = make_float4(res[0], res[1], res[2], res[3]);
}

extern "C" void kernel_launch(void* const* d_in, const int* in_sizes, int n_in,
                              void* d_out, int out_size, void* d_ws, size_t ws_size,
                              hipStream_t stream) {
    const float* src  = (const float*)d_in[0];   // [1,1,D,H,W]
    const float* flow = (const float*)d_in[1];   // [1,3,D,H,W]
    // d_in[2] identity grid: unused (recomputed)
    float* out = (float*)d_out;

    if (ws_size >= WS_NEEDED) {
        unsigned int* tab = (unsigned int*)d_ws;
        pack2_kernel<<<(ZP * HH * (WW / 4)) / 256, 256, 0, stream>>>(src, tab);
        warp2_kernel<<<DHW / 4 / 256, 256, 0, stream>>>(tab, flow, out);
    } else {
        warp_direct_kernel<<<DHW / 4 / 256, 256, 0, stream>>>(src, flow, out);
    }
}

// Round 2
// 178.563 us; speedup vs baseline: 1.0293x; 1.0293x over previous
//
#include <hip/hip_runtime.h>

// Spatial transformer: trilinear warp of src by flow, border padding.
// D=160, H=192, W=160.  u = (idx + flow) * S/(S-1) - 0.5, clamp, trilinear.
//
// Lineage:
//   R5: 4-parity bf16 table, 2x8B gather (same line)  -> 51us
//   R6: same table, 1x16B gather                      -> 50us  (req count free)
//   R7: z-parity table (2 lines/voxel) + d-slab order -> 61us, FETCH 71->45MB
// Conclusion: cost ~ DISTINCT LINES per voxel; R7's ordering DID make the
// table cache-resident (FETCH drop) but doubled lines. R8 = R6's 1-line
// 4-parity gather + R7's (d-slab x h-half) block order + pack swizzled so
// XCD k builds the zp slab it will gather from => ~2.5MB active window/XCD
// fits the 4MB XCD L2.

#define DD 160
#define HH 192
#define WW 160
#define DHW (DD * HH * WW)
#define ZP (DD / 2)   /* 80 */
#define YP (HH / 2)   /* 96 */
#define COPY_ENTRIES (ZP * YP * WW)            /* 1,228,800 entries x 8B */
#define WS_NEEDED (4ULL * COPY_ENTRIES * 8ULL) /* 39,321,600 B */

typedef unsigned int u32x4 __attribute__((ext_vector_type(4)));

__device__ __forceinline__ unsigned short bf16_rn(float f) {
    unsigned int u = __float_as_uint(f);
    return (unsigned short)((u + 0x7FFFu + ((u >> 16) & 1u)) >> 16);
}

// ---------------- prepass: build 4 parity-packed bf16 stencil copies ----------------
// copy(cz,cy) entry [zp][yp][x] (2 uints):
//   u0 = bf(z0,y0,x) | bf(z1,y0,x)<<16
//   u1 = bf(z0,y1,x) | bf(z1,y1,x)<<16
// where z0=2*zp+cz, z1=min(z0+1,DD-1), y0=2*yp+cy, y1=min(y0+1,HH-1).
// XCD swizzle: 15 blocks cover one zp slab; XCD k builds zp in [10k,10k+10),
// matching warp_kernel's d-slab ownership so the slab is warm in that L2.
__global__ __launch_bounds__(256) void pack_kernel(
    const float* __restrict__ src, unsigned int* __restrict__ tab)
{
    int b = blockIdx.x;                            // grid 1200 = 8 * 150
    int nb = (b & 7) * 150 + (b >> 3);
    int t = nb * 256 + (int)threadIdx.x;           // 307,200 threads
    int xq  = t % (WW / 4);
    int rem = t / (WW / 4);
    int yp  = rem % YP;
    int zp  = rem / YP;                            // [0,80): zp slab of 10 per XCD
    int x = xq * 4;

    int zs[3] = { 2 * zp, 2 * zp + 1, min(2 * zp + 2, DD - 1) };
    int ys[3] = { 2 * yp, 2 * yp + 1, min(2 * yp + 2, HH - 1) };

    float4 r[3][3];
    #pragma unroll
    for (int i = 0; i < 3; ++i)
        #pragma unroll
        for (int j = 0; j < 3; ++j)
            r[i][j] = *(const float4*)(src + ((size_t)zs[i] * HH + ys[j]) * WW + x);

    #pragma unroll
    for (int cz = 0; cz < 2; ++cz)
        #pragma unroll
        for (int cy = 0; cy < 2; ++cy) {
            unsigned int e[8];
            #pragma unroll
            for (int k = 0; k < 4; ++k) {
                float a = ((const float*)&r[cz    ][cy    ])[k];
                float b2 = ((const float*)&r[cz + 1][cy    ])[k];
                float c = ((const float*)&r[cz    ][cy + 1])[k];
                float d = ((const float*)&r[cz + 1][cy + 1])[k];
                e[2 * k]     = (unsigned int)bf16_rn(a) | ((unsigned int)bf16_rn(b2) << 16);
                e[2 * k + 1] = (unsigned int)bf16_rn(c) | ((unsigned int)bf16_rn(d) << 16);
            }
            unsigned int* dst = tab +
                ((size_t)(cz * 2 + cy) * COPY_ENTRIES + ((size_t)zp * YP + yp) * WW + x) * 2;
            *(uint4*)(dst)     = make_uint4(e[0], e[1], e[2], e[3]);
            *(uint4*)(dst + 4) = make_uint4(e[4], e[5], e[6], e[7]);
        }
}

// ---------------- main: 1x 16B gather per voxel, L2-resident slab ----------------
__global__ __launch_bounds__(256) void warp_kernel(
    const unsigned int* __restrict__ tab,
    const float* __restrict__ flow,
    float* __restrict__ out)
{
    // Block -> voxel mapping (R7's, kept): XCD k owns d in [20k, 20k+20);
    // within the slab, h-half 0 fully, then h-half 1. ~256 resident blocks
    // per XCD => ~17 d-planes x half-y active => 4 copies x ~10 zp x ~49 yp
    // x 160 x 8B ~ 2.5 MB of table: fits 4MB XCD L2.
    int b  = blockIdx.x;                 // grid 4800 = 8 * 2 * 20 * 15
    int k  = b & 7;                      // XCD
    int j  = b >> 3;                     // [0,600)
    int hh = j / 300;                    // h half: 0 or 1
    int jj = j - hh * 300;               // [0,300)
    int dq = jj / 15;                    // [0,20)
    int r  = jj - dq * 15;               // [0,15): 15 blocks per half-plane

    int base = (k * 20 + dq) * (HH * WW) + hh * ((HH / 2) * WW)
             + (r * 256 + (int)threadIdx.x) * 4;

    int w = base % WW;
    int tmp = base / WW;
    int h = tmp % HH;
    int d = tmp / HH;

    const float4 f0  = *(const float4*)(flow + base);           // -> D/z
    const float4 f1  = *(const float4*)(flow + DHW + base);     // -> H/y
    const float4 f2v = *(const float4*)(flow + 2 * DHW + base); // -> W/x
    const float* fl0 = (const float*)&f0;
    const float* fl1 = (const float*)&f1;
    const float* fl2 = (const float*)&f2v;

    const float SX = (float)WW / (float)(WW - 1);
    const float SY = (float)HH / (float)(HH - 1);
    const float SZ = (float)DD / (float)(DD - 1);

    float fx[4], fy[4], fz[4];
    bool  xe[4];
    const unsigned int* pp[4];

    // ---- phase 1: addresses & weights ----
    #pragma unroll
    for (int v = 0; v < 4; ++v) {
        float ux = fmaf((float)(w + v) + fl2[v], SX, -0.5f);
        float uy = fmaf((float)h + fl1[v],       SY, -0.5f);
        float uz = fmaf((float)d + fl0[v],       SZ, -0.5f);
        ux = fminf(fmaxf(ux, 0.0f), (float)(WW - 1));
        uy = fminf(fmaxf(uy, 0.0f), (float)(HH - 1));
        uz = fminf(fmaxf(uz, 0.0f), (float)(DD - 1));
        float x0f = floorf(ux), y0f = floorf(uy), z0f = floorf(uz);
        fx[v] = ux - x0f; fy[v] = uy - y0f; fz[v] = uz - z0f;
        int x0 = (int)x0f, y0 = (int)y0f, z0 = (int)z0f;
        int zp = z0 >> 1, cz = z0 & 1;
        int yp = y0 >> 1, cy = y0 & 1;
        int xb = min(x0, WW - 2);          // entries xb, xb+1
        xe[v] = (x0 == WW - 1);            // clamped: both x taps = entry xb+1
        pp[v] = tab + ((size_t)((cz << 1) | cy) * COPY_ENTRIES
                       + ((size_t)zp * YP + yp) * WW + xb) * 2;
    }

    // ---- phase 2: ONE dwordx4 per voxel (addr is 8B-aligned; HW needs 4B) ----
    u32x4 q[4];
    #pragma unroll
    for (int v = 0; v < 4; ++v)
        asm volatile("global_load_dwordx4 %0, %1, off"
                     : "=v"(q[v]) : "v"(pp[v]));

    // ---- phase 3: progressive waits (vmcnt retires in issue order) + interp ----
    float res[4];
    #pragma unroll
    for (int v = 0; v < 4; ++v) {
        if (v == 0) asm volatile("s_waitcnt vmcnt(3)" : "+v"(q[0]) :: "memory");
        if (v == 1) asm volatile("s_waitcnt vmcnt(2)" : "+v"(q[1]) :: "memory");
        if (v == 2) asm volatile("s_waitcnt vmcnt(1)" : "+v"(q[2]) :: "memory");
        if (v == 3) asm volatile("s_waitcnt vmcnt(0)" : "+v"(q[3]) :: "memory");

        unsigned int lox = q[v].x;   // entry xb  : (z0,y0),(z1,y0)
        unsigned int loy = q[v].y;   //            (z0,y1),(z1,y1)
        unsigned int hix = q[v].z;   // entry xb+1
        unsigned int hiy = q[v].w;
        unsigned int a0 = xe[v] ? hix : lox;
        unsigned int a1 = xe[v] ? hiy : loy;

        float c000 = __uint_as_float(a0 << 16);
        float c100 = __uint_as_float(a0 & 0xFFFF0000u);
        float c010 = __uint_as_float(a1 << 16);
        float c110 = __uint_as_float(a1 & 0xFFFF0000u);
        float c001 = __uint_as_float(hix << 16);
        float c101 = __uint_as_float(hix & 0xFFFF0000u);
        float c011 = __uint_as_float(hiy << 16);
        float c111 = __uint_as_float(hiy & 0xFFFF0000u);

        float r00 = fmaf(fx[v], c001 - c000, c000);
        float r01 = fmaf(fx[v], c011 - c010, c010);
        float r10 = fmaf(fx[v], c101 - c100, c100);
        float r11 = fmaf(fx[v], c111 - c110, c110);
        float r0  = fmaf(fy[v], r01 - r00, r00);
        float r1  = fmaf(fy[v], r11 - r10, r10);
        res[v]    = fmaf(fz[v], r1 - r0, r0);
    }

    *(float4*)(out + base) = make_float4(res[0], res[1], res[2], res[3]);
}

// ---------------- fallback (proven R2 kernel) if ws too small ----------------
struct __align__(4) F2 { float a, b; };

__global__ __launch_bounds__(256) void warp_direct_kernel(
    const float* __restrict__ src,
    const float* __restrict__ flow,
    float* __restrict__ out)
{
    int b = blockIdx.x;
    int nb = (b & 7) * 600 + (b >> 3);
    int base = (nb * 256 + (int)threadIdx.x) * 4;

    int w = base % WW;
    int tmp = base / WW;
    int h = tmp % HH;
    int d = tmp / HH;

    const float4 f0  = *(const float4*)(flow + base);
    const float4 f1  = *(const float4*)(flow + DHW + base);
    const float4 f2v = *(const float4*)(flow + 2 * DHW + base);
    const float* f0p = (const float*)&f0;
    const float* f1p = (const float*)&f1;
    const float* f2p = (const float*)&f2v;

    const float SX = (float)WW / (float)(WW - 1);
    const float SY = (float)HH / (float)(HH - 1);
    const float SZ = (float)DD / (float)(DD - 1);

    float res[4];
    #pragma unroll
    for (int v = 0; v < 4; ++v) {
        float ux = fmaf((float)(w + v) + f2p[v], SX, -0.5f);
        float uy = fmaf((float)h + f1p[v],       SY, -0.5f);
        float uz = fmaf((float)d + f0p[v],       SZ, -0.5f);
        ux = fminf(fmaxf(ux, 0.0f), (float)(WW - 1));
        uy = fminf(fmaxf(uy, 0.0f), (float)(HH - 1));
        uz = fminf(fmaxf(uz, 0.0f), (float)(DD - 1));
        float x0f = floorf(ux), y0f = floorf(uy), z0f = floorf(uz);
        float fx = ux - x0f, fy = uy - y0f, fz = uz - z0f;
        int x0 = (int)x0f, y0 = (int)y0f, z0 = (int)z0f;
        int y1 = min(y0 + 1, HH - 1);
        int z1 = min(z0 + 1, DD - 1);
        int xb = min(x0, WW - 2);
        bool xe = (x0 == WW - 1);
        F2 q00 = *(const F2*)(src + ((size_t)z0 * HH + y0) * WW + xb);
        F2 q01 = *(const F2*)(src + ((size_t)z0 * HH + y1) * WW + xb);
        F2 q10 = *(const F2*)(src + ((size_t)z1 * HH + y0) * WW + xb);
        F2 q11 = *(const F2*)(src + ((size_t)z1 * HH + y1) * WW + xb);
        float c000 = xe ? q00.b : q00.a, c001 = q00.b;
        float c010 = xe ? q01.b : q01.a, c011 = q01.b;
        float c100 = xe ? q10.b : q10.a, c101 = q10.b;
        float c110 = xe ? q11.b : q11.a, c111 = q11.b;
        float r00 = fmaf(fx, c001 - c000, c000);
        float r01 = fmaf(fx, c011 - c010, c010);
        float r10 = fmaf(fx, c101 - c100, c100);
        float r11 = fmaf(fx, c111 - c110, c110);
        float r0  = fmaf(fy, r01 - r00, r00);
        float r1  = fmaf(fy, r11 - r10, r10);
        res[v]    = fmaf(fz, r1 - r0, r0);
    }
    *(float4*)(out + base) = make_float4(res[0], res[1], res[2], res[3]);
}

extern "C" void kernel_launch(void* const* d_in, const int* in_sizes, int n_in,
                              void* d_out, int out_size, void* d_ws, size_t ws_size,
                              hipStream_t stream) {
    const float* src  = (const float*)d_in[0];   // [1,1,D,H,W]
    const float* flow = (const float*)d_in[1];   // [1,3,D,H,W]
    // d_in[2] identity grid: unused (recomputed)
    float* out = (float*)d_out;

    if (ws_size >= WS_NEEDED) {
        unsigned int* tab = (unsigned int*)d_ws;
        pack_kernel<<<(ZP * YP * (WW / 4)) / 256, 256, 0, stream>>>(src, tab);
        warp_kernel<<<DHW / 4 / 256, 256, 0, stream>>>(tab, flow, out);
    } else {
        warp_direct_kernel<<<DHW / 4 / 256, 256, 0, stream>>>(src, flow, out);
    }
}